// Round 1
// 142.869 us; speedup vs baseline: 1.1034x; 1.1034x over previous
//
#include <hip/hip_runtime.h>
#include <hip/hip_bf16.h>

constexpr int KD = 1024;
constexpr int ND = 512;
constexpr int NT = 16;           // K tiles of 64
constexpr float EPSV = 1e-5f;

using f32x4  = __attribute__((ext_vector_type(4))) float;
using bf16x8 = __attribute__((ext_vector_type(8))) short;
using u16x8  = __attribute__((ext_vector_type(8))) unsigned short;

__device__ __forceinline__ unsigned short f2bf(float f) {
  unsigned int u = __builtin_bit_cast(unsigned int, f);
  return (unsigned short)((u + 0x7fffu + ((u >> 16) & 1u)) >> 16);  // RNE
}

__device__ __forceinline__ u16x8 pack8(float4 a, float4 b) {
  u16x8 v;
  v[0] = f2bf(a.x); v[1] = f2bf(a.y); v[2] = f2bf(a.z); v[3] = f2bf(a.w);
  v[4] = f2bf(b.x); v[5] = f2bf(b.y); v[6] = f2bf(b.z); v[7] = f2bf(b.w);
  return v;
}

__device__ __forceinline__ unsigned short cvt1(float f) {
  __hip_bfloat16 h = __float2bfloat16(f);          // compiler-lowered RNE cvt
  return __builtin_bit_cast(unsigned short, h);
}

__device__ __forceinline__ void gload16(const void* g, void* l) {
  __builtin_amdgcn_global_load_lds(
      (const __attribute__((address_space(1))) void*)g,
      (__attribute__((address_space(3))) void*)l, 16, 0, 0);
}

#define WAITV8()  asm volatile("s_waitcnt vmcnt(8)" ::: "memory")
#define WAITV0()  asm volatile("s_waitcnt vmcnt(0)" ::: "memory")
#define LGKM0()   do { asm volatile("s_waitcnt lgkmcnt(0)" ::: "memory"); \
                       __builtin_amdgcn_sched_barrier(0); } while (0)
#define SCHEDB()  __builtin_amdgcn_sched_barrier(0)

__global__ void wconvert_kernel(const float* __restrict__ w,
                                unsigned short* __restrict__ wb) {
  int i = (blockIdx.x * blockDim.x + threadIdx.x) * 8;
  float4 a = *reinterpret_cast<const float4*>(w + i);
  float4 b = *reinterpret_cast<const float4*>(w + i + 4);
  *reinterpret_cast<u16x8*>(wb + i) = pack8(a, b);
}

// ===== Fused GEMM(128x512, full N) + bias + LN + scale + softmax ============
// 8 waves (2M x 4N), wave tile 64x128, acc[4][8] frags.
// LDS: Bs dbuf 512x64 bf16 = 128 KB, As single 128x64 bf16 = 16 KB -> 144 KB.
// Row = 128 B = 8 chunks of 16 B; chunk c of row stored at c^(row&7).
// A: reg-staged (4 float4/thread), cvt->bf16, ds_write_b64, extra barrier/tile.
// B: pre-swizzled global src, linear gload_lds dest (proven pattern).
// Epilogue fully in-register; row stats via 16-lane shfl_xor + LDS [128][4].
__global__ __launch_bounds__(512, 2)
void fused_kernel(const float* __restrict__ x,
                  const unsigned short* __restrict__ wb,
                  const float* __restrict__ bias,
                  const float* __restrict__ gamma,
                  const float* __restrict__ beta,
                  const float* __restrict__ scalep,
                  float* __restrict__ out) {
  __shared__ unsigned short As[128 * 64];      // 16 KB, single buffer
  __shared__ unsigned short Bs[2][512 * 64];   // 64 KB each

  const int tid  = threadIdx.x;
  const int lane = tid & 63;
  const int wid  = tid >> 6;        // 0..7
  const int wr   = wid >> 2;        // M half (0..1): rows wr*64..+63
  const int wcq  = wid & 3;         // N quarter (0..3): cols wcq*128..+127
  const int l15  = lane & 15;
  const int lg   = lane >> 4;       // 0..3

  const long bm  = (long)blockIdx.x * 128;

  f32x4 acc[4][8] = {};

  // ---- A staging map: load q, lane l -> row_local = wid*16 + q*4 + (l>>4),
  //      f32 col = (l&15)*4  (+ t*64 per tile)
  const int arow0 = wid * 16 + lg;
  const float* asrc = x + (bm + arow0) * KD + l15 * 4;
  int aw[4];
  #pragma unroll
  for (int q = 0; q < 4; ++q) {
    int row = arow0 + q * 4;
    aw[q] = row * 128 + (((l15 >> 1) ^ (row & 7)) * 16) + ((l15 & 1) * 8);
  }

  // ---- B staging src (pre-swizzled global source, linear gload_lds dest) ----
  int bsrc[8];
  #pragma unroll
  for (int p = 0; p < 8; ++p) {
    int n = p * 64 + (tid >> 3);
    int u = (tid & 7) ^ (n & 7);
    bsrc[p] = n * KD + u * 8;
  }

  // ---- fragment read byte-addrs (ks=0; ks=1 is ^64) ----
  int ard[4], brd[8];
  #pragma unroll
  for (int i = 0; i < 4; ++i) {
    int row = wr * 64 + i * 16 + l15;
    ard[i] = row * 128 + (lg ^ (row & 7)) * 16;
  }
  #pragma unroll
  for (int i = 0; i < 8; ++i) {
    int n = wcq * 128 + i * 16 + l15;
    brd[i] = n * 128 + (lg ^ (n & 7)) * 16;
  }

#define ISSUE_A(t) do { \
    qa0 = *reinterpret_cast<const float4*>(asrc + (t) * 64 + 0 * 4 * KD); \
    qa1 = *reinterpret_cast<const float4*>(asrc + (t) * 64 + 1 * 4 * KD); \
    qa2 = *reinterpret_cast<const float4*>(asrc + (t) * 64 + 2 * 4 * KD); \
    qa3 = *reinterpret_cast<const float4*>(asrc + (t) * 64 + 3 * 4 * KD); } while (0)

#define ISSUE_B(t, bufi) do { \
    gload16(wb + bsrc[0] + (t) * 64, (char*)Bs[bufi] + 0 * 8192 + tid * 16); \
    gload16(wb + bsrc[1] + (t) * 64, (char*)Bs[bufi] + 1 * 8192 + tid * 16); \
    gload16(wb + bsrc[2] + (t) * 64, (char*)Bs[bufi] + 2 * 8192 + tid * 16); \
    gload16(wb + bsrc[3] + (t) * 64, (char*)Bs[bufi] + 3 * 8192 + tid * 16); \
    gload16(wb + bsrc[4] + (t) * 64, (char*)Bs[bufi] + 4 * 8192 + tid * 16); \
    gload16(wb + bsrc[5] + (t) * 64, (char*)Bs[bufi] + 5 * 8192 + tid * 16); \
    gload16(wb + bsrc[6] + (t) * 64, (char*)Bs[bufi] + 6 * 8192 + tid * 16); \
    gload16(wb + bsrc[7] + (t) * 64, (char*)Bs[bufi] + 7 * 8192 + tid * 16); } while (0)

#define WA1(qr, qi) do { \
    union { unsigned short s[4]; unsigned long long v; } c_; \
    c_.s[0] = cvt1(qr.x); c_.s[1] = cvt1(qr.y); \
    c_.s[2] = cvt1(qr.z); c_.s[3] = cvt1(qr.w); \
    *reinterpret_cast<unsigned long long*>((char*)As + aw[qi]) = c_.v; } while (0)

#define WRITE_A() do { WA1(qa0, 0); WA1(qa1, 1); WA1(qa2, 2); WA1(qa3, 3); } while (0)

#define COMPUTE(bufi) do { \
    const char* ab_ = (const char*)As; \
    const char* bb_ = (const char*)Bs[bufi]; \
    _Pragma("unroll") \
    for (int ks = 0; ks < 2; ++ks) { \
      const int kx_ = ks * 64; \
      bf16x8 b0_ = *reinterpret_cast<const bf16x8*>(bb_ + (brd[0] ^ kx_)); \
      bf16x8 b1_ = *reinterpret_cast<const bf16x8*>(bb_ + (brd[1] ^ kx_)); \
      bf16x8 b2_ = *reinterpret_cast<const bf16x8*>(bb_ + (brd[2] ^ kx_)); \
      bf16x8 b3_ = *reinterpret_cast<const bf16x8*>(bb_ + (brd[3] ^ kx_)); \
      bf16x8 b4_ = *reinterpret_cast<const bf16x8*>(bb_ + (brd[4] ^ kx_)); \
      bf16x8 b5_ = *reinterpret_cast<const bf16x8*>(bb_ + (brd[5] ^ kx_)); \
      bf16x8 b6_ = *reinterpret_cast<const bf16x8*>(bb_ + (brd[6] ^ kx_)); \
      bf16x8 b7_ = *reinterpret_cast<const bf16x8*>(bb_ + (brd[7] ^ kx_)); \
      _Pragma("unroll") \
      for (int mi = 0; mi < 4; ++mi) { \
        bf16x8 af_ = *reinterpret_cast<const bf16x8*>(ab_ + (ard[mi] ^ kx_)); \
        acc[mi][0] = __builtin_amdgcn_mfma_f32_16x16x32_bf16(af_, b0_, acc[mi][0], 0, 0, 0); \
        acc[mi][1] = __builtin_amdgcn_mfma_f32_16x16x32_bf16(af_, b1_, acc[mi][1], 0, 0, 0); \
        acc[mi][2] = __builtin_amdgcn_mfma_f32_16x16x32_bf16(af_, b2_, acc[mi][2], 0, 0, 0); \
        acc[mi][3] = __builtin_amdgcn_mfma_f32_16x16x32_bf16(af_, b3_, acc[mi][3], 0, 0, 0); \
        acc[mi][4] = __builtin_amdgcn_mfma_f32_16x16x32_bf16(af_, b4_, acc[mi][4], 0, 0, 0); \
        acc[mi][5] = __builtin_amdgcn_mfma_f32_16x16x32_bf16(af_, b5_, acc[mi][5], 0, 0, 0); \
        acc[mi][6] = __builtin_amdgcn_mfma_f32_16x16x32_bf16(af_, b6_, acc[mi][6], 0, 0, 0); \
        acc[mi][7] = __builtin_amdgcn_mfma_f32_16x16x32_bf16(af_, b7_, acc[mi][7], 0, 0, 0); \
      } \
    } } while (0)

  float4 qa0, qa1, qa2, qa3;

  // ---- prologue: stage tile 0 ----
  ISSUE_A(0);    SCHEDB();
  ISSUE_B(0, 0); SCHEDB();
  WAITV8();            // 4 A loads retired (8 B dma outstanding)
  WRITE_A();
  WAITV0();            // B(0) landed
  LGKM0();
  __builtin_amdgcn_s_barrier();
  SCHEDB();

  for (int t = 0; t < NT; ++t) {
    const int cur = t & 1;
    const int tp  = (t + 1 < NT) ? t + 1 : NT - 1;  // clamp keeps ledger constant
    ISSUE_A(tp);          SCHEDB();
    ISSUE_B(tp, cur ^ 1); SCHEDB();
    COMPUTE(cur);         // hides A/B load latency under 64 MFMAs
    SCHEDB();
    __builtin_amdgcn_s_barrier();   // all waves done reading As(t)
    SCHEDB();
    WAITV8();             // A(t+1) in regs
    WRITE_A();            // As <- tile t+1
    WAITV0();             // B(t+1) landed in Bs[cur^1]
    LGKM0();
    __builtin_amdgcn_s_barrier();   // publish As(t+1) + Bs[cur^1]
    SCHEDB();
  }

  // ================= fused epilogue: bias + LN + scale + softmax ============
  // scratch carved from As (all GEMM LDS traffic drained above)
  float* redS = (float*)As;            // [128][5] padded partial sums
  float* redQ = redS + 640;            // [128][5] padded partial sumsq / expsum
  float* rowA = redQ + 640;            // [128] mu, later rowmax
  float* rowB = rowA + 128;            // [128] rstd, later 1/expsum

  const int col0 = wcq * 128 + l15;
  const float sc = scalep[0];
  float bs8[8], gs8[8], bb8[8];
  #pragma unroll
  for (int ni = 0; ni < 8; ++ni) {
    bs8[ni] = bias[col0 + ni * 16];
    gs8[ni] = gamma[col0 + ni * 16] * sc;
    bb8[ni] = beta[col0 + ni * 16] * sc;
  }

  // ---- bias add + per-row sum / sumsq ----
  #pragma unroll
  for (int mi = 0; mi < 4; ++mi) {
    #pragma unroll
    for (int j = 0; j < 4; ++j) {
      float s = 0.f, q = 0.f;
      #pragma unroll
      for (int ni = 0; ni < 8; ++ni) {
        float v = acc[mi][ni][j] + bs8[ni];
        acc[mi][ni][j] = v;
        s += v;
        q = fmaf(v, v, q);
      }
      #pragma unroll
      for (int m = 1; m < 16; m <<= 1) {
        s += __shfl_xor(s, m, 64);
        q += __shfl_xor(q, m, 64);
      }
      if (l15 == 0) {
        int r = wr * 64 + mi * 16 + lg * 4 + j;
        redS[r * 5 + wcq] = s;
        redQ[r * 5 + wcq] = q;
      }
    }
  }
  __syncthreads();
  if (tid < 128) {
    float s = redS[tid * 5 + 0] + redS[tid * 5 + 1] + redS[tid * 5 + 2] + redS[tid * 5 + 3];
    float q = redQ[tid * 5 + 0] + redQ[tid * 5 + 1] + redQ[tid * 5 + 2] + redQ[tid * 5 + 3];
    float mu = s * (1.f / ND);
    rowA[tid] = mu;
    rowB[tid] = rsqrtf(q * (1.f / ND) - mu * mu + EPSV);
  }
  __syncthreads();

  // ---- normalize + scale; per-row max ----
  #pragma unroll
  for (int mi = 0; mi < 4; ++mi) {
    #pragma unroll
    for (int j = 0; j < 4; ++j) {
      int r = wr * 64 + mi * 16 + lg * 4 + j;
      float mu = rowA[r], rs = rowB[r];
      float pm = -3.402823466e38f;
      #pragma unroll
      for (int ni = 0; ni < 8; ++ni) {
        float v = (acc[mi][ni][j] - mu) * rs;
        v = fmaf(v, gs8[ni], bb8[ni]);
        acc[mi][ni][j] = v;
        pm = fmaxf(pm, v);
      }
      #pragma unroll
      for (int m = 1; m < 16; m <<= 1) pm = fmaxf(pm, __shfl_xor(pm, m, 64));
      if (l15 == 0) redS[r * 5 + wcq] = pm;
    }
  }
  __syncthreads();
  if (tid < 128) {
    rowA[tid] = fmaxf(fmaxf(redS[tid * 5 + 0], redS[tid * 5 + 1]),
                      fmaxf(redS[tid * 5 + 2], redS[tid * 5 + 3]));
  }
  __syncthreads();

  // ---- exp + per-row sum ----
  #pragma unroll
  for (int mi = 0; mi < 4; ++mi) {
    #pragma unroll
    for (int j = 0; j < 4; ++j) {
      int r = wr * 64 + mi * 16 + lg * 4 + j;
      float rmx = rowA[r];
      float ps = 0.f;
      #pragma unroll
      for (int ni = 0; ni < 8; ++ni) {
        float e = __expf(acc[mi][ni][j] - rmx);
        acc[mi][ni][j] = e;
        ps += e;
      }
      #pragma unroll
      for (int m = 1; m < 16; m <<= 1) ps += __shfl_xor(ps, m, 64);
      if (l15 == 0) redQ[r * 5 + wcq] = ps;
    }
  }
  __syncthreads();
  if (tid < 128) {
    rowB[tid] = 1.f / (redQ[tid * 5 + 0] + redQ[tid * 5 + 1] +
                       redQ[tid * 5 + 2] + redQ[tid * 5 + 3]);
  }
  __syncthreads();

  // ---- store out f32 (non-temporal: don't evict L2-resident B) ----
  #pragma unroll
  for (int mi = 0; mi < 4; ++mi) {
    #pragma unroll
    for (int j = 0; j < 4; ++j) {
      int r = wr * 64 + mi * 16 + lg * 4 + j;
      float rd = rowB[r];
      float* op = out + (bm + r) * ND + col0;
      #pragma unroll
      for (int ni = 0; ni < 8; ++ni)
        __builtin_nontemporal_store(acc[mi][ni][j] * rd, op + ni * 16);
    }
  }
#undef ISSUE_A
#undef ISSUE_B
#undef WA1
#undef WRITE_A
#undef COMPUTE
}

// trivial last-resort fallback (ws too small; not expected in this harness)
__global__ void fused_fallback(const float* __restrict__ x,
                               const float* __restrict__ wf,
                               const float* __restrict__ bias,
                               const float* __restrict__ gamma,
                               const float* __restrict__ beta,
                               const float* __restrict__ scalep,
                               float* __restrict__ out) {
  long row = blockIdx.x;
  int t = threadIdx.x;
  float s = 0.f;
  const float* xr = x + row * KD;
  const float* wr_ = wf + (size_t)t * KD;
  for (int k = 0; k < KD; ++k) s += xr[k] * wr_[k];
  s += bias[t];
  __shared__ float buf[ND];
  buf[t] = s;
  __syncthreads();
  __shared__ float red[2];
  if (t == 0) {
    float sum = 0.f, sq = 0.f;
    for (int i = 0; i < ND; ++i) { sum += buf[i]; sq += buf[i] * buf[i]; }
    float mu = sum / ND;
    red[0] = mu;
    red[1] = rsqrtf(sq / ND - mu * mu + EPSV);
  }
  __syncthreads();
  float zv = (s - red[0]) * red[1] * gamma[t] * scalep[0] + beta[t] * scalep[0];
  buf[t] = zv;
  __syncthreads();
  __shared__ float red2[2];
  if (t == 0) {
    float mxv = -3.4e38f;
    for (int i = 0; i < ND; ++i) mxv = fmaxf(mxv, buf[i]);
    float den = 0.f;
    for (int i = 0; i < ND; ++i) den += __expf(buf[i] - mxv);
    red2[0] = mxv; red2[1] = 1.f / den;
  }
  __syncthreads();
  out[row * ND + t] = __expf(zv - red2[0]) * red2[1];
}

extern "C" void kernel_launch(void* const* d_in, const int* in_sizes, int n_in,
                              void* d_out, int out_size, void* d_ws, size_t ws_size,
                              hipStream_t stream) {
  const float* x     = (const float*)d_in[0];
  const float* w     = (const float*)d_in[1];
  const float* bias  = (const float*)d_in[2];
  const float* gamma = (const float*)d_in[3];
  const float* beta  = (const float*)d_in[4];
  const float* scale = (const float*)d_in[5];
  float* out = (float*)d_out;

  const int Mrows = in_sizes[0] / KD;                                  // 65536
  const size_t wb_bytes = (size_t)ND * KD * sizeof(unsigned short);    // 1 MB

  if (ws_size >= wb_bytes) {
    unsigned short* wbuf = (unsigned short*)d_ws;
    wconvert_kernel<<<(ND * KD) / (256 * 8), 256, 0, stream>>>(w, wbuf);
    fused_kernel<<<Mrows / 128, 512, 0, stream>>>(x, wbuf, bias, gamma, beta,
                                                  scale, out);
  } else {
    fused_fallback<<<Mrows, ND, 0, stream>>>(x, w, bias, gamma, beta, scale, out);
  }
}

// Round 2
// 140.450 us; speedup vs baseline: 1.1224x; 1.0172x over previous
//
#include <hip/hip_runtime.h>
#include <hip/hip_bf16.h>

constexpr int KD = 1024;
constexpr int ND = 512;
constexpr int NT = 16;           // K tiles of 64
constexpr float EPSV = 1e-5f;

using f32x4  = __attribute__((ext_vector_type(4))) float;
using bf16x8 = __attribute__((ext_vector_type(8))) short;
using u16x8  = __attribute__((ext_vector_type(8))) unsigned short;

__device__ __forceinline__ unsigned short f2bf(float f) {
  unsigned int u = __builtin_bit_cast(unsigned int, f);
  return (unsigned short)((u + 0x7fffu + ((u >> 16) & 1u)) >> 16);  // RNE
}

__device__ __forceinline__ u16x8 pack8(float4 a, float4 b) {
  u16x8 v;
  v[0] = f2bf(a.x); v[1] = f2bf(a.y); v[2] = f2bf(a.z); v[3] = f2bf(a.w);
  v[4] = f2bf(b.x); v[5] = f2bf(b.y); v[6] = f2bf(b.z); v[7] = f2bf(b.w);
  return v;
}

__device__ __forceinline__ unsigned short cvt1(float f) {
  __hip_bfloat16 h = __float2bfloat16(f);          // compiler-lowered RNE cvt
  return __builtin_bit_cast(unsigned short, h);
}

__device__ __forceinline__ float bf2f(unsigned short s) {
  unsigned int u = (unsigned int)s << 16;
  return __builtin_bit_cast(float, u);
}

__device__ __forceinline__ void gload16(const void* g, void* l) {
  __builtin_amdgcn_global_load_lds(
      (const __attribute__((address_space(1))) void*)g,
      (__attribute__((address_space(3))) void*)l, 16, 0, 0);
}

#define WAITV8()  asm volatile("s_waitcnt vmcnt(8)" ::: "memory")
#define WAITV0()  asm volatile("s_waitcnt vmcnt(0)" ::: "memory")
#define LGKM0()   do { asm volatile("s_waitcnt lgkmcnt(0)" ::: "memory"); \
                       __builtin_amdgcn_sched_barrier(0); } while (0)
#define SCHEDB()  __builtin_amdgcn_sched_barrier(0)

__global__ void wconvert_kernel(const float* __restrict__ w,
                                unsigned short* __restrict__ wb) {
  int i = (blockIdx.x * blockDim.x + threadIdx.x) * 8;
  float4 a = *reinterpret_cast<const float4*>(w + i);
  float4 b = *reinterpret_cast<const float4*>(w + i + 4);
  *reinterpret_cast<u16x8*>(wb + i) = pack8(a, b);
}

// ===== Fused GEMM(128x512, full N) + bias + LN + scale + softmax ============
// 8 waves (2M x 4N), wave tile 64x128, acc[4][8] frags.
// LDS: Bs dbuf 512x64 bf16 = 128 KB, As dbuf 128x64 bf16 = 32 KB -> 160 KB
// (full CU budget; AITER attn precedent uses 160 KB).
// Row = 128 B = 8 chunks of 16 B; chunk c of row stored at c^(row&7).
// Phased K-loop (T3/T4/T5): per tile two {issue || ds_read -> lgkm0 ->
// setprio(1) 32 MFMA setprio(0)} phases, WRITE_A to the other buffer,
// ONE barrier per tile. B drain is L2-hot (cheap); A covered by ~2 phases.
__global__ __launch_bounds__(512, 2)
void fused_kernel(const float* __restrict__ x,
                  const unsigned short* __restrict__ wb,
                  const float* __restrict__ bias,
                  const float* __restrict__ gamma,
                  const float* __restrict__ beta,
                  const float* __restrict__ scalep,
                  float* __restrict__ out) {
  __shared__ unsigned short As[2][128 * 64];   // 16 KB each
  __shared__ unsigned short Bs[2][512 * 64];   // 64 KB each

  const int tid  = threadIdx.x;
  const int lane = tid & 63;
  const int wid  = tid >> 6;        // 0..7
  const int wr   = wid >> 2;        // M half (0..1): rows wr*64..+63
  const int wcq  = wid & 3;         // N quarter (0..3): cols wcq*128..+127
  const int l15  = lane & 15;
  const int lg   = lane >> 4;       // 0..3

  const long bm  = (long)blockIdx.x * 128;

  f32x4 acc[4][8] = {};

  // ---- A staging map: load q, lane l -> row_local = wid*16 + q*4 + (l>>4),
  //      f32 col = (l&15)*4  (+ t*64 per tile)
  const int arow0 = wid * 16 + lg;
  const float* asrc = x + (bm + arow0) * KD + l15 * 4;
  int aw[4];
  #pragma unroll
  for (int q = 0; q < 4; ++q) {
    int row = arow0 + q * 4;
    aw[q] = row * 128 + (((l15 >> 1) ^ (row & 7)) * 16) + ((l15 & 1) * 8);
  }

  // ---- B staging src (pre-swizzled global source, linear gload_lds dest) ----
  int bsrc[8];
  #pragma unroll
  for (int p = 0; p < 8; ++p) {
    int n = p * 64 + (tid >> 3);
    int u = (tid & 7) ^ (n & 7);
    bsrc[p] = n * KD + u * 8;
  }

  // ---- fragment read byte-addrs (ks=0; ks=1 is ^64) ----
  int ard[4], brd[8];
  #pragma unroll
  for (int i = 0; i < 4; ++i) {
    int row = wr * 64 + i * 16 + l15;
    ard[i] = row * 128 + (lg ^ (row & 7)) * 16;
  }
  #pragma unroll
  for (int i = 0; i < 8; ++i) {
    int n = wcq * 128 + i * 16 + l15;
    brd[i] = n * 128 + (lg ^ (n & 7)) * 16;
  }

#define ISSUE_A(t) do { \
    qa0 = *reinterpret_cast<const float4*>(asrc + (t) * 64 + 0 * 4 * KD); \
    qa1 = *reinterpret_cast<const float4*>(asrc + (t) * 64 + 1 * 4 * KD); \
    qa2 = *reinterpret_cast<const float4*>(asrc + (t) * 64 + 2 * 4 * KD); \
    qa3 = *reinterpret_cast<const float4*>(asrc + (t) * 64 + 3 * 4 * KD); } while (0)

#define ISSUE_B(t, bufi) do { \
    gload16(wb + bsrc[0] + (t) * 64, (char*)Bs[bufi] + 0 * 8192 + tid * 16); \
    gload16(wb + bsrc[1] + (t) * 64, (char*)Bs[bufi] + 1 * 8192 + tid * 16); \
    gload16(wb + bsrc[2] + (t) * 64, (char*)Bs[bufi] + 2 * 8192 + tid * 16); \
    gload16(wb + bsrc[3] + (t) * 64, (char*)Bs[bufi] + 3 * 8192 + tid * 16); \
    gload16(wb + bsrc[4] + (t) * 64, (char*)Bs[bufi] + 4 * 8192 + tid * 16); \
    gload16(wb + bsrc[5] + (t) * 64, (char*)Bs[bufi] + 5 * 8192 + tid * 16); \
    gload16(wb + bsrc[6] + (t) * 64, (char*)Bs[bufi] + 6 * 8192 + tid * 16); \
    gload16(wb + bsrc[7] + (t) * 64, (char*)Bs[bufi] + 7 * 8192 + tid * 16); } while (0)

#define WA1(qr, qi, bufi) do { \
    union { unsigned short s[4]; unsigned long long v; } c_; \
    c_.s[0] = cvt1(qr.x); c_.s[1] = cvt1(qr.y); \
    c_.s[2] = cvt1(qr.z); c_.s[3] = cvt1(qr.w); \
    *reinterpret_cast<unsigned long long*>((char*)As[bufi] + aw[qi]) = c_.v; } while (0)

#define WRITE_A(bufi) do { const int wb_ = (bufi); \
    WA1(qa0, 0, wb_); WA1(qa1, 1, wb_); WA1(qa2, 2, wb_); WA1(qa3, 3, wb_); } while (0)

  // One phase: 12 ds_read (4 A-frags + 8 B-frags) then 32 MFMA under setprio.
#define PHASE(ks, bufc) do { \
    const char* ab_ = (const char*)As[bufc]; \
    const char* bb_ = (const char*)Bs[bufc]; \
    const int kx_ = (ks) * 64; \
    bf16x8 b0_ = *reinterpret_cast<const bf16x8*>(bb_ + (brd[0] ^ kx_)); \
    bf16x8 b1_ = *reinterpret_cast<const bf16x8*>(bb_ + (brd[1] ^ kx_)); \
    bf16x8 b2_ = *reinterpret_cast<const bf16x8*>(bb_ + (brd[2] ^ kx_)); \
    bf16x8 b3_ = *reinterpret_cast<const bf16x8*>(bb_ + (brd[3] ^ kx_)); \
    bf16x8 b4_ = *reinterpret_cast<const bf16x8*>(bb_ + (brd[4] ^ kx_)); \
    bf16x8 b5_ = *reinterpret_cast<const bf16x8*>(bb_ + (brd[5] ^ kx_)); \
    bf16x8 b6_ = *reinterpret_cast<const bf16x8*>(bb_ + (brd[6] ^ kx_)); \
    bf16x8 b7_ = *reinterpret_cast<const bf16x8*>(bb_ + (brd[7] ^ kx_)); \
    bf16x8 a0_ = *reinterpret_cast<const bf16x8*>(ab_ + (ard[0] ^ kx_)); \
    bf16x8 a1_ = *reinterpret_cast<const bf16x8*>(ab_ + (ard[1] ^ kx_)); \
    bf16x8 a2_ = *reinterpret_cast<const bf16x8*>(ab_ + (ard[2] ^ kx_)); \
    bf16x8 a3_ = *reinterpret_cast<const bf16x8*>(ab_ + (ard[3] ^ kx_)); \
    LGKM0(); \
    __builtin_amdgcn_s_setprio(1); \
    acc[0][0] = __builtin_amdgcn_mfma_f32_16x16x32_bf16(a0_, b0_, acc[0][0], 0, 0, 0); \
    acc[0][1] = __builtin_amdgcn_mfma_f32_16x16x32_bf16(a0_, b1_, acc[0][1], 0, 0, 0); \
    acc[0][2] = __builtin_amdgcn_mfma_f32_16x16x32_bf16(a0_, b2_, acc[0][2], 0, 0, 0); \
    acc[0][3] = __builtin_amdgcn_mfma_f32_16x16x32_bf16(a0_, b3_, acc[0][3], 0, 0, 0); \
    acc[0][4] = __builtin_amdgcn_mfma_f32_16x16x32_bf16(a0_, b4_, acc[0][4], 0, 0, 0); \
    acc[0][5] = __builtin_amdgcn_mfma_f32_16x16x32_bf16(a0_, b5_, acc[0][5], 0, 0, 0); \
    acc[0][6] = __builtin_amdgcn_mfma_f32_16x16x32_bf16(a0_, b6_, acc[0][6], 0, 0, 0); \
    acc[0][7] = __builtin_amdgcn_mfma_f32_16x16x32_bf16(a0_, b7_, acc[0][7], 0, 0, 0); \
    acc[1][0] = __builtin_amdgcn_mfma_f32_16x16x32_bf16(a1_, b0_, acc[1][0], 0, 0, 0); \
    acc[1][1] = __builtin_amdgcn_mfma_f32_16x16x32_bf16(a1_, b1_, acc[1][1], 0, 0, 0); \
    acc[1][2] = __builtin_amdgcn_mfma_f32_16x16x32_bf16(a1_, b2_, acc[1][2], 0, 0, 0); \
    acc[1][3] = __builtin_amdgcn_mfma_f32_16x16x32_bf16(a1_, b3_, acc[1][3], 0, 0, 0); \
    acc[1][4] = __builtin_amdgcn_mfma_f32_16x16x32_bf16(a1_, b4_, acc[1][4], 0, 0, 0); \
    acc[1][5] = __builtin_amdgcn_mfma_f32_16x16x32_bf16(a1_, b5_, acc[1][5], 0, 0, 0); \
    acc[1][6] = __builtin_amdgcn_mfma_f32_16x16x32_bf16(a1_, b6_, acc[1][6], 0, 0, 0); \
    acc[1][7] = __builtin_amdgcn_mfma_f32_16x16x32_bf16(a1_, b7_, acc[1][7], 0, 0, 0); \
    acc[2][0] = __builtin_amdgcn_mfma_f32_16x16x32_bf16(a2_, b0_, acc[2][0], 0, 0, 0); \
    acc[2][1] = __builtin_amdgcn_mfma_f32_16x16x32_bf16(a2_, b1_, acc[2][1], 0, 0, 0); \
    acc[2][2] = __builtin_amdgcn_mfma_f32_16x16x32_bf16(a2_, b2_, acc[2][2], 0, 0, 0); \
    acc[2][3] = __builtin_amdgcn_mfma_f32_16x16x32_bf16(a2_, b3_, acc[2][3], 0, 0, 0); \
    acc[2][4] = __builtin_amdgcn_mfma_f32_16x16x32_bf16(a2_, b4_, acc[2][4], 0, 0, 0); \
    acc[2][5] = __builtin_amdgcn_mfma_f32_16x16x32_bf16(a2_, b5_, acc[2][5], 0, 0, 0); \
    acc[2][6] = __builtin_amdgcn_mfma_f32_16x16x32_bf16(a2_, b6_, acc[2][6], 0, 0, 0); \
    acc[2][7] = __builtin_amdgcn_mfma_f32_16x16x32_bf16(a2_, b7_, acc[2][7], 0, 0, 0); \
    acc[3][0] = __builtin_amdgcn_mfma_f32_16x16x32_bf16(a3_, b0_, acc[3][0], 0, 0, 0); \
    acc[3][1] = __builtin_amdgcn_mfma_f32_16x16x32_bf16(a3_, b1_, acc[3][1], 0, 0, 0); \
    acc[3][2] = __builtin_amdgcn_mfma_f32_16x16x32_bf16(a3_, b2_, acc[3][2], 0, 0, 0); \
    acc[3][3] = __builtin_amdgcn_mfma_f32_16x16x32_bf16(a3_, b3_, acc[3][3], 0, 0, 0); \
    acc[3][4] = __builtin_amdgcn_mfma_f32_16x16x32_bf16(a3_, b4_, acc[3][4], 0, 0, 0); \
    acc[3][5] = __builtin_amdgcn_mfma_f32_16x16x32_bf16(a3_, b5_, acc[3][5], 0, 0, 0); \
    acc[3][6] = __builtin_amdgcn_mfma_f32_16x16x32_bf16(a3_, b6_, acc[3][6], 0, 0, 0); \
    acc[3][7] = __builtin_amdgcn_mfma_f32_16x16x32_bf16(a3_, b7_, acc[3][7], 0, 0, 0); \
    __builtin_amdgcn_s_setprio(0); \
    SCHEDB(); } while (0)

  float4 qa0, qa1, qa2, qa3;

  // ---- prologue: stage tile 0 into buf 0 ----
  ISSUE_A(0);    SCHEDB();
  ISSUE_B(0, 0); SCHEDB();
  WAITV8();            // 4 A loads retired (8 B dma outstanding)
  WRITE_A(0);
  WAITV0();            // B(0) landed
  LGKM0();
  __builtin_amdgcn_s_barrier();
  SCHEDB();

  for (int t = 0; t < NT; ++t) {
    const int cur = t & 1;
    const int tp  = (t + 1 < NT) ? t + 1 : NT - 1;  // clamp keeps ledger constant
    // phase 0: A(t+1) issue hides under ks=0 MFMAs
    ISSUE_A(tp);          SCHEDB();
    PHASE(0, cur);
    // phase 1: B(t+1) dma hides under ks=1 MFMAs
    ISSUE_B(tp, cur ^ 1); SCHEDB();
    PHASE(1, cur);
    WAITV8();             // A(t+1) in regs (8 B dma outstanding)
    WRITE_A(cur ^ 1);     // other buffer: no barrier needed first
    WAITV0();             // B(t+1) landed (L2-hot, issued a phase ago)
    LGKM0();
    __builtin_amdgcn_s_barrier();   // publish As/Bs[cur^1]; one barrier/tile
    SCHEDB();
  }

  // ================= fused epilogue: bias + LN + scale + softmax ============
  // scratch carved from As (all GEMM LDS traffic drained above)
  float* redS = (float*)As[0];         // [128][5] padded partial sums
  float* redQ = redS + 640;            // [128][5] padded partial sumsq / expsum
  float* rowA = redQ + 640;            // [128] mu, later rowmax
  float* rowB = rowA + 128;            // [128] rstd, later 1/expsum

  const int col0 = wcq * 128 + l15;
  const float sc = scalep[0];
  float bs8[8], gs8[8], bb8[8];
  #pragma unroll
  for (int ni = 0; ni < 8; ++ni) {
    bs8[ni] = bias[col0 + ni * 16];
    gs8[ni] = gamma[col0 + ni * 16] * sc;
    bb8[ni] = beta[col0 + ni * 16] * sc;
  }

  // ---- bias add + per-row sum / sumsq ----
  #pragma unroll
  for (int mi = 0; mi < 4; ++mi) {
    #pragma unroll
    for (int j = 0; j < 4; ++j) {
      float s = 0.f, q = 0.f;
      #pragma unroll
      for (int ni = 0; ni < 8; ++ni) {
        float v = acc[mi][ni][j] + bs8[ni];
        acc[mi][ni][j] = v;
        s += v;
        q = fmaf(v, v, q);
      }
      #pragma unroll
      for (int m = 1; m < 16; m <<= 1) {
        s += __shfl_xor(s, m, 64);
        q += __shfl_xor(q, m, 64);
      }
      if (l15 == 0) {
        int r = wr * 64 + mi * 16 + lg * 4 + j;
        redS[r * 5 + wcq] = s;
        redQ[r * 5 + wcq] = q;
      }
    }
  }
  __syncthreads();
  if (tid < 128) {
    float s = redS[tid * 5 + 0] + redS[tid * 5 + 1] + redS[tid * 5 + 2] + redS[tid * 5 + 3];
    float q = redQ[tid * 5 + 0] + redQ[tid * 5 + 1] + redQ[tid * 5 + 2] + redQ[tid * 5 + 3];
    float mu = s * (1.f / ND);
    rowA[tid] = mu;
    rowB[tid] = rsqrtf(q * (1.f / ND) - mu * mu + EPSV);
  }
  __syncthreads();

  // ---- normalize + scale; per-row max ----
  #pragma unroll
  for (int mi = 0; mi < 4; ++mi) {
    #pragma unroll
    for (int j = 0; j < 4; ++j) {
      int r = wr * 64 + mi * 16 + lg * 4 + j;
      float mu = rowA[r], rs = rowB[r];
      float pm = -3.402823466e38f;
      #pragma unroll
      for (int ni = 0; ni < 8; ++ni) {
        float v = (acc[mi][ni][j] - mu) * rs;
        v = fmaf(v, gs8[ni], bb8[ni]);
        acc[mi][ni][j] = v;
        pm = fmaxf(pm, v);
      }
      #pragma unroll
      for (int m = 1; m < 16; m <<= 1) pm = fmaxf(pm, __shfl_xor(pm, m, 64));
      if (l15 == 0) redS[r * 5 + wcq] = pm;
    }
  }
  __syncthreads();
  if (tid < 128) {
    rowA[tid] = fmaxf(fmaxf(redS[tid * 5 + 0], redS[tid * 5 + 1]),
                      fmaxf(redS[tid * 5 + 2], redS[tid * 5 + 3]));
  }
  __syncthreads();

  // ---- exp + per-row sum ----
  #pragma unroll
  for (int mi = 0; mi < 4; ++mi) {
    #pragma unroll
    for (int j = 0; j < 4; ++j) {
      int r = wr * 64 + mi * 16 + lg * 4 + j;
      float rmx = rowA[r];
      float ps = 0.f;
      #pragma unroll
      for (int ni = 0; ni < 8; ++ni) {
        float e = __expf(acc[mi][ni][j] - rmx);
        acc[mi][ni][j] = e;
        ps += e;
      }
      #pragma unroll
      for (int m = 1; m < 16; m <<= 1) ps += __shfl_xor(ps, m, 64);
      if (l15 == 0) redQ[r * 5 + wcq] = ps;
    }
  }
  __syncthreads();
  if (tid < 128) {
    rowB[tid] = 1.f / (redQ[tid * 5 + 0] + redQ[tid * 5 + 1] +
                       redQ[tid * 5 + 2] + redQ[tid * 5 + 3]);
  }
  __syncthreads();

  // ---- store out f32 (non-temporal: don't evict L2-resident B) ----
  #pragma unroll
  for (int mi = 0; mi < 4; ++mi) {
    #pragma unroll
    for (int j = 0; j < 4; ++j) {
      int r = wr * 64 + mi * 16 + lg * 4 + j;
      float rd = rowB[r];
      float* op = out + (bm + r) * ND + col0;
      #pragma unroll
      for (int ni = 0; ni < 8; ++ni)
        __builtin_nontemporal_store(acc[mi][ni][j] * rd, op + ni * 16);
    }
  }
#undef ISSUE_A
#undef ISSUE_B
#undef WA1
#undef WRITE_A
#undef PHASE
}

// trivial last-resort fallback (ws too small; not expected in this harness)
__global__ void fused_fallback(const float* __restrict__ x,
                               const float* __restrict__ wf,
                               const float* __restrict__ bias,
                               const float* __restrict__ gamma,
                               const float* __restrict__ beta,
                               const float* __restrict__ scalep,
                               float* __restrict__ out) {
  long row = blockIdx.x;
  int t = threadIdx.x;
  float s = 0.f;
  const float* xr = x + row * KD;
  const float* wr_ = wf + (size_t)t * KD;
  for (int k = 0; k < KD; ++k) s += xr[k] * wr_[k];
  s += bias[t];
  __shared__ float buf[ND];
  buf[t] = s;
  __syncthreads();
  __shared__ float red[2];
  if (t == 0) {
    float sum = 0.f, sq = 0.f;
    for (int i = 0; i < ND; ++i) { sum += buf[i]; sq += buf[i] * buf[i]; }
    float mu = sum / ND;
    red[0] = mu;
    red[1] = rsqrtf(sq / ND - mu * mu + EPSV);
  }
  __syncthreads();
  float zv = (s - red[0]) * red[1] * gamma[t] * scalep[0] + beta[t] * scalep[0];
  buf[t] = zv;
  __syncthreads();
  __shared__ float red2[2];
  if (t == 0) {
    float mxv = -3.4e38f;
    for (int i = 0; i < ND; ++i) mxv = fmaxf(mxv, buf[i]);
    float den = 0.f;
    for (int i = 0; i < ND; ++i) den += __expf(buf[i] - mxv);
    red2[0] = mxv; red2[1] = 1.f / den;
  }
  __syncthreads();
  out[row * ND + t] = __expf(zv - red2[0]) * red2[1];
}

extern "C" void kernel_launch(void* const* d_in, const int* in_sizes, int n_in,
                              void* d_out, int out_size, void* d_ws, size_t ws_size,
                              hipStream_t stream) {
  const float* x     = (const float*)d_in[0];
  const float* w     = (const float*)d_in[1];
  const float* bias  = (const float*)d_in[2];
  const float* gamma = (const float*)d_in[3];
  const float* beta  = (const float*)d_in[4];
  const float* scale = (const float*)d_in[5];
  float* out = (float*)d_out;

  const int Mrows = in_sizes[0] / KD;                                  // 65536
  const size_t wb_bytes = (size_t)ND * KD * sizeof(unsigned short);    // 1 MB

  if (ws_size >= wb_bytes) {
    unsigned short* wbuf = (unsigned short*)d_ws;
    wconvert_kernel<<<(ND * KD) / (256 * 8), 256, 0, stream>>>(w, wbuf);
    fused_kernel<<<Mrows / 128, 512, 0, stream>>>(x, wbuf, bias, gamma, beta,
                                                  scale, out);
  } else {
    fused_fallback<<<Mrows, ND, 0, stream>>>(x, w, bias, gamma, beta, scale, out);
  }
}

// Round 3
// 139.129 us; speedup vs baseline: 1.1331x; 1.0095x over previous
//
#include <hip/hip_runtime.h>
#include <hip/hip_bf16.h>

constexpr int KD = 1024;
constexpr int ND = 512;
constexpr int NT = 16;           // K tiles of 64
constexpr float EPSV = 1e-5f;

using f32x4  = __attribute__((ext_vector_type(4))) float;
using bf16x8 = __attribute__((ext_vector_type(8))) short;
using u16x8  = __attribute__((ext_vector_type(8))) unsigned short;

__device__ __forceinline__ unsigned short f2bf(float f) {
  unsigned int u = __builtin_bit_cast(unsigned int, f);
  return (unsigned short)((u + 0x7fffu + ((u >> 16) & 1u)) >> 16);  // RNE
}

__device__ __forceinline__ u16x8 pack8(float4 a, float4 b) {
  u16x8 v;
  v[0] = f2bf(a.x); v[1] = f2bf(a.y); v[2] = f2bf(a.z); v[3] = f2bf(a.w);
  v[4] = f2bf(b.x); v[5] = f2bf(b.y); v[6] = f2bf(b.z); v[7] = f2bf(b.w);
  return v;
}

__device__ __forceinline__ unsigned short cvt1(float f) {
  __hip_bfloat16 h = __float2bfloat16(f);          // compiler-lowered RNE cvt
  return __builtin_bit_cast(unsigned short, h);
}

__device__ __forceinline__ void gload16(const void* g, void* l) {
  __builtin_amdgcn_global_load_lds(
      (const __attribute__((address_space(1))) void*)g,
      (__attribute__((address_space(3))) void*)l, 16, 0, 0);
}

#define WAITV4()  asm volatile("s_waitcnt vmcnt(4)" ::: "memory")
#define WAITV0()  asm volatile("s_waitcnt vmcnt(0)" ::: "memory")
#define LGKM0()   do { asm volatile("s_waitcnt lgkmcnt(0)" ::: "memory"); \
                       __builtin_amdgcn_sched_barrier(0); } while (0)
#define SCHEDB()  __builtin_amdgcn_sched_barrier(0)

__global__ void wconvert_kernel(const float* __restrict__ w,
                                unsigned short* __restrict__ wb) {
  int i = (blockIdx.x * blockDim.x + threadIdx.x) * 8;
  float4 a = *reinterpret_cast<const float4*>(w + i);
  float4 b = *reinterpret_cast<const float4*>(w + i + 4);
  *reinterpret_cast<u16x8*>(wb + i) = pack8(a, b);
}

// ===== Fused GEMM(128x512, full N) + bias + LN + scale + softmax ============
// R3 change: 1024 threads / 16 waves (2M x 8N), wave tile 64x64, acc[4][4]
// (64 VGPR) -> 4 waves/SIMD (was 2). Same 160 KB dbuf LDS, same staging
// pattern; per-thread load counts halve (2 A-float4, 4 B-gload_lds).
// Theory: R2 showed schedule changes move nothing at 2 waves/SIMD; the
// stall is latency with no TLP to hide it (Guideline 1).
__global__ __launch_bounds__(1024, 4)
void fused_kernel(const float* __restrict__ x,
                  const unsigned short* __restrict__ wb,
                  const float* __restrict__ bias,
                  const float* __restrict__ gamma,
                  const float* __restrict__ beta,
                  const float* __restrict__ scalep,
                  float* __restrict__ out) {
  __shared__ unsigned short As[2][128 * 64];   // 16 KB each
  __shared__ unsigned short Bs[2][512 * 64];   // 64 KB each

  const int tid  = threadIdx.x;
  const int lane = tid & 63;
  const int wid  = tid >> 6;        // 0..15
  const int wr   = wid >> 3;        // M half (0..1): rows wr*64..+63
  const int wcn  = wid & 7;         // N eighth (0..7): cols wcn*64..+63
  const int l15  = lane & 15;
  const int lg   = lane >> 4;       // 0..3

  const long bm  = (long)blockIdx.x * 128;

  f32x4 acc[4][4] = {};

  // ---- A staging map: load q(0..1), lane l -> row_local = wid*8 + q*4 + lg,
  //      f32 col = l15*4  (+ t*64 per tile). 16 lanes x 16 B = 256 B/row. ----
  const int arow0 = wid * 8 + lg;
  const float* asrc = x + (bm + arow0) * KD + l15 * 4;
  int aw[2];
  #pragma unroll
  for (int q = 0; q < 2; ++q) {
    int row = arow0 + q * 4;
    aw[q] = row * 128 + (((l15 >> 1) ^ (row & 7)) * 16) + ((l15 & 1) * 8);
  }

  // ---- B staging src (pre-swizzled global source, linear gload_lds dest) ----
  int bsrc[4];
  #pragma unroll
  for (int p = 0; p < 4; ++p) {
    int n = p * 128 + (tid >> 3);
    int u = (tid & 7) ^ (n & 7);
    bsrc[p] = n * KD + u * 8;
  }

  // ---- fragment read byte-addrs (ks=0; ks=1 is ^64) ----
  int ard[4], brd[4];
  #pragma unroll
  for (int i = 0; i < 4; ++i) {
    int row = wr * 64 + i * 16 + l15;
    ard[i] = row * 128 + (lg ^ (row & 7)) * 16;
  }
  #pragma unroll
  for (int i = 0; i < 4; ++i) {
    int n = wcn * 64 + i * 16 + l15;
    brd[i] = n * 128 + (lg ^ (n & 7)) * 16;
  }

#define ISSUE_A(t) do { \
    qa0 = *reinterpret_cast<const float4*>(asrc + (t) * 64 + 0 * 4 * KD); \
    qa1 = *reinterpret_cast<const float4*>(asrc + (t) * 64 + 1 * 4 * KD); } while (0)

#define ISSUE_B(t, bufi) do { \
    gload16(wb + bsrc[0] + (t) * 64, (char*)Bs[bufi] + 0 * 16384 + tid * 16); \
    gload16(wb + bsrc[1] + (t) * 64, (char*)Bs[bufi] + 1 * 16384 + tid * 16); \
    gload16(wb + bsrc[2] + (t) * 64, (char*)Bs[bufi] + 2 * 16384 + tid * 16); \
    gload16(wb + bsrc[3] + (t) * 64, (char*)Bs[bufi] + 3 * 16384 + tid * 16); } while (0)

#define WA1(qr, qi, bufi) do { \
    union { unsigned short s[4]; unsigned long long v; } c_; \
    c_.s[0] = cvt1(qr.x); c_.s[1] = cvt1(qr.y); \
    c_.s[2] = cvt1(qr.z); c_.s[3] = cvt1(qr.w); \
    *reinterpret_cast<unsigned long long*>((char*)As[bufi] + aw[qi]) = c_.v; } while (0)

#define WRITE_A(bufi) do { const int wb_ = (bufi); \
    WA1(qa0, 0, wb_); WA1(qa1, 1, wb_); } while (0)

  // One phase: 8 ds_read (4 A-frags + 4 B-frags) then 16 MFMA under setprio.
#define PHASE(ks, bufc) do { \
    const char* ab_ = (const char*)As[bufc]; \
    const char* bb_ = (const char*)Bs[bufc]; \
    const int kx_ = (ks) * 64; \
    bf16x8 b0_ = *reinterpret_cast<const bf16x8*>(bb_ + (brd[0] ^ kx_)); \
    bf16x8 b1_ = *reinterpret_cast<const bf16x8*>(bb_ + (brd[1] ^ kx_)); \
    bf16x8 b2_ = *reinterpret_cast<const bf16x8*>(bb_ + (brd[2] ^ kx_)); \
    bf16x8 b3_ = *reinterpret_cast<const bf16x8*>(bb_ + (brd[3] ^ kx_)); \
    bf16x8 a0_ = *reinterpret_cast<const bf16x8*>(ab_ + (ard[0] ^ kx_)); \
    bf16x8 a1_ = *reinterpret_cast<const bf16x8*>(ab_ + (ard[1] ^ kx_)); \
    bf16x8 a2_ = *reinterpret_cast<const bf16x8*>(ab_ + (ard[2] ^ kx_)); \
    bf16x8 a3_ = *reinterpret_cast<const bf16x8*>(ab_ + (ard[3] ^ kx_)); \
    LGKM0(); \
    __builtin_amdgcn_s_setprio(1); \
    acc[0][0] = __builtin_amdgcn_mfma_f32_16x16x32_bf16(a0_, b0_, acc[0][0], 0, 0, 0); \
    acc[0][1] = __builtin_amdgcn_mfma_f32_16x16x32_bf16(a0_, b1_, acc[0][1], 0, 0, 0); \
    acc[0][2] = __builtin_amdgcn_mfma_f32_16x16x32_bf16(a0_, b2_, acc[0][2], 0, 0, 0); \
    acc[0][3] = __builtin_amdgcn_mfma_f32_16x16x32_bf16(a0_, b3_, acc[0][3], 0, 0, 0); \
    acc[1][0] = __builtin_amdgcn_mfma_f32_16x16x32_bf16(a1_, b0_, acc[1][0], 0, 0, 0); \
    acc[1][1] = __builtin_amdgcn_mfma_f32_16x16x32_bf16(a1_, b1_, acc[1][1], 0, 0, 0); \
    acc[1][2] = __builtin_amdgcn_mfma_f32_16x16x32_bf16(a1_, b2_, acc[1][2], 0, 0, 0); \
    acc[1][3] = __builtin_amdgcn_mfma_f32_16x16x32_bf16(a1_, b3_, acc[1][3], 0, 0, 0); \
    acc[2][0] = __builtin_amdgcn_mfma_f32_16x16x32_bf16(a2_, b0_, acc[2][0], 0, 0, 0); \
    acc[2][1] = __builtin_amdgcn_mfma_f32_16x16x32_bf16(a2_, b1_, acc[2][1], 0, 0, 0); \
    acc[2][2] = __builtin_amdgcn_mfma_f32_16x16x32_bf16(a2_, b2_, acc[2][2], 0, 0, 0); \
    acc[2][3] = __builtin_amdgcn_mfma_f32_16x16x32_bf16(a2_, b3_, acc[2][3], 0, 0, 0); \
    acc[3][0] = __builtin_amdgcn_mfma_f32_16x16x32_bf16(a3_, b0_, acc[3][0], 0, 0, 0); \
    acc[3][1] = __builtin_amdgcn_mfma_f32_16x16x32_bf16(a3_, b1_, acc[3][1], 0, 0, 0); \
    acc[3][2] = __builtin_amdgcn_mfma_f32_16x16x32_bf16(a3_, b2_, acc[3][2], 0, 0, 0); \
    acc[3][3] = __builtin_amdgcn_mfma_f32_16x16x32_bf16(a3_, b3_, acc[3][3], 0, 0, 0); \
    __builtin_amdgcn_s_setprio(0); \
    SCHEDB(); } while (0)

  float4 qa0, qa1;

  // ---- prologue: stage tile 0 into buf 0 ----
  ISSUE_A(0);    SCHEDB();
  ISSUE_B(0, 0); SCHEDB();
  WAITV4();            // 2 A loads retired (4 B dma outstanding)
  WRITE_A(0);
  WAITV0();            // B(0) landed
  LGKM0();
  __builtin_amdgcn_s_barrier();
  SCHEDB();

  for (int t = 0; t < NT; ++t) {
    const int cur = t & 1;
    const int tp  = (t + 1 < NT) ? t + 1 : NT - 1;  // clamp keeps ledger constant
    ISSUE_A(tp);          SCHEDB();
    ISSUE_B(tp, cur ^ 1); SCHEDB();
    PHASE(0, cur);
    PHASE(1, cur);
    WAITV4();             // A(t+1) in regs (4 B dma outstanding)
    WRITE_A(cur ^ 1);
    WAITV0();             // B(t+1) landed (issued 2 phases ago, L2-hot)
    LGKM0();
    __builtin_amdgcn_s_barrier();   // publish As/Bs[cur^1]; one barrier/tile
    SCHEDB();
  }

  // ================= fused epilogue: bias + LN + scale + softmax ============
  // scratch carved from As (all GEMM LDS traffic drained above)
  float* redS = (float*)As[0];         // [128][9] padded partial sums
  float* redQ = redS + 1152;           // [128][9] partial sumsq / expsum
  float* rowA = redQ + 1152;           // [128] mu, later rowmax
  float* rowB = rowA + 128;            // [128] rstd, later 1/expsum

  const int col0 = wcn * 64 + l15;
  const float sc = scalep[0];
  float bs4[4], gs4[4], bb4[4];
  #pragma unroll
  for (int ni = 0; ni < 4; ++ni) {
    bs4[ni] = bias[col0 + ni * 16];
    gs4[ni] = gamma[col0 + ni * 16] * sc;
    bb4[ni] = beta[col0 + ni * 16] * sc;
  }

  // ---- bias add + per-row sum / sumsq ----
  #pragma unroll
  for (int mi = 0; mi < 4; ++mi) {
    #pragma unroll
    for (int j = 0; j < 4; ++j) {
      float s = 0.f, q = 0.f;
      #pragma unroll
      for (int ni = 0; ni < 4; ++ni) {
        float v = acc[mi][ni][j] + bs4[ni];
        acc[mi][ni][j] = v;
        s += v;
        q = fmaf(v, v, q);
      }
      #pragma unroll
      for (int m = 1; m < 16; m <<= 1) {
        s += __shfl_xor(s, m, 64);
        q += __shfl_xor(q, m, 64);
      }
      if (l15 == 0) {
        int r = wr * 64 + mi * 16 + lg * 4 + j;
        redS[r * 9 + wcn] = s;
        redQ[r * 9 + wcn] = q;
      }
    }
  }
  __syncthreads();
  if (tid < 128) {
    float s = 0.f, q = 0.f;
    #pragma unroll
    for (int k = 0; k < 8; ++k) { s += redS[tid * 9 + k]; q += redQ[tid * 9 + k]; }
    float mu = s * (1.f / ND);
    rowA[tid] = mu;
    rowB[tid] = rsqrtf(q * (1.f / ND) - mu * mu + EPSV);
  }
  __syncthreads();

  // ---- normalize + scale; per-row max ----
  #pragma unroll
  for (int mi = 0; mi < 4; ++mi) {
    #pragma unroll
    for (int j = 0; j < 4; ++j) {
      int r = wr * 64 + mi * 16 + lg * 4 + j;
      float mu = rowA[r], rs = rowB[r];
      float pm = -3.402823466e38f;
      #pragma unroll
      for (int ni = 0; ni < 4; ++ni) {
        float v = (acc[mi][ni][j] - mu) * rs;
        v = fmaf(v, gs4[ni], bb4[ni]);
        acc[mi][ni][j] = v;
        pm = fmaxf(pm, v);
      }
      #pragma unroll
      for (int m = 1; m < 16; m <<= 1) pm = fmaxf(pm, __shfl_xor(pm, m, 64));
      if (l15 == 0) redS[r * 9 + wcn] = pm;
    }
  }
  __syncthreads();
  if (tid < 128) {
    float m0 = fmaxf(fmaxf(redS[tid * 9 + 0], redS[tid * 9 + 1]),
                     fmaxf(redS[tid * 9 + 2], redS[tid * 9 + 3]));
    float m1 = fmaxf(fmaxf(redS[tid * 9 + 4], redS[tid * 9 + 5]),
                     fmaxf(redS[tid * 9 + 6], redS[tid * 9 + 7]));
    rowA[tid] = fmaxf(m0, m1);
  }
  __syncthreads();

  // ---- exp + per-row sum ----
  #pragma unroll
  for (int mi = 0; mi < 4; ++mi) {
    #pragma unroll
    for (int j = 0; j < 4; ++j) {
      int r = wr * 64 + mi * 16 + lg * 4 + j;
      float rmx = rowA[r];
      float ps = 0.f;
      #pragma unroll
      for (int ni = 0; ni < 4; ++ni) {
        float e = __expf(acc[mi][ni][j] - rmx);
        acc[mi][ni][j] = e;
        ps += e;
      }
      #pragma unroll
      for (int m = 1; m < 16; m <<= 1) ps += __shfl_xor(ps, m, 64);
      if (l15 == 0) redQ[r * 9 + wcn] = ps;
    }
  }
  __syncthreads();
  if (tid < 128) {
    float s = 0.f;
    #pragma unroll
    for (int k = 0; k < 8; ++k) s += redQ[tid * 9 + k];
    rowB[tid] = 1.f / s;
  }
  __syncthreads();

  // ---- store out f32 (non-temporal: don't evict L2-resident B) ----
  #pragma unroll
  for (int mi = 0; mi < 4; ++mi) {
    #pragma unroll
    for (int j = 0; j < 4; ++j) {
      int r = wr * 64 + mi * 16 + lg * 4 + j;
      float rd = rowB[r];
      float* op = out + (bm + r) * ND + col0;
      #pragma unroll
      for (int ni = 0; ni < 4; ++ni)
        __builtin_nontemporal_store(acc[mi][ni][j] * rd, op + ni * 16);
    }
  }
#undef ISSUE_A
#undef ISSUE_B
#undef WA1
#undef WRITE_A
#undef PHASE
}

// trivial last-resort fallback (ws too small; not expected in this harness)
__global__ void fused_fallback(const float* __restrict__ x,
                               const float* __restrict__ wf,
                               const float* __restrict__ bias,
                               const float* __restrict__ gamma,
                               const float* __restrict__ beta,
                               const float* __restrict__ scalep,
                               float* __restrict__ out) {
  long row = blockIdx.x;
  int t = threadIdx.x;
  float s = 0.f;
  const float* xr = x + row * KD;
  const float* wr_ = wf + (size_t)t * KD;
  for (int k = 0; k < KD; ++k) s += xr[k] * wr_[k];
  s += bias[t];
  __shared__ float buf[ND];
  buf[t] = s;
  __syncthreads();
  __shared__ float red[2];
  if (t == 0) {
    float sum = 0.f, sq = 0.f;
    for (int i = 0; i < ND; ++i) { sum += buf[i]; sq += buf[i] * buf[i]; }
    float mu = sum / ND;
    red[0] = mu;
    red[1] = rsqrtf(sq / ND - mu * mu + EPSV);
  }
  __syncthreads();
  float zv = (s - red[0]) * red[1] * gamma[t] * scalep[0] + beta[t] * scalep[0];
  buf[t] = zv;
  __syncthreads();
  __shared__ float red2[2];
  if (t == 0) {
    float mxv = -3.4e38f;
    for (int i = 0; i < ND; ++i) mxv = fmaxf(mxv, buf[i]);
    float den = 0.f;
    for (int i = 0; i < ND; ++i) den += __expf(buf[i] - mxv);
    red2[0] = mxv; red2[1] = 1.f / den;
  }
  __syncthreads();
  out[row * ND + t] = __expf(zv - red2[0]) * red2[1];
}

extern "C" void kernel_launch(void* const* d_in, const int* in_sizes, int n_in,
                              void* d_out, int out_size, void* d_ws, size_t ws_size,
                              hipStream_t stream) {
  const float* x     = (const float*)d_in[0];
  const float* w     = (const float*)d_in[1];
  const float* bias  = (const float*)d_in[2];
  const float* gamma = (const float*)d_in[3];
  const float* beta  = (const float*)d_in[4];
  const float* scale = (const float*)d_in[5];
  float* out = (float*)d_out;

  const int Mrows = in_sizes[0] / KD;                                  // 65536
  const size_t wb_bytes = (size_t)ND * KD * sizeof(unsigned short);    // 1 MB

  if (ws_size >= wb_bytes) {
    unsigned short* wbuf = (unsigned short*)d_ws;
    wconvert_kernel<<<(ND * KD) / (256 * 8), 256, 0, stream>>>(w, wbuf);
    fused_kernel<<<Mrows / 128, 1024, 0, stream>>>(x, wbuf, bias, gamma, beta,
                                                   scale, out);
  } else {
    fused_fallback<<<Mrows, ND, 0, stream>>>(x, w, bias, gamma, beta, scale, out);
  }
}

// Round 4
// 130.213 us; speedup vs baseline: 1.2106x; 1.0685x over previous
//
#include <hip/hip_runtime.h>
#include <hip/hip_bf16.h>

constexpr int KD = 1024;
constexpr int ND = 512;
constexpr int NT = 32;           // K tiles of 32
constexpr float EPSV = 1e-5f;

using f32x4  = __attribute__((ext_vector_type(4))) float;
using bf16x8 = __attribute__((ext_vector_type(8))) short;
using u16x8  = __attribute__((ext_vector_type(8))) unsigned short;

__device__ __forceinline__ unsigned short f2bf(float f) {
  unsigned int u = __builtin_bit_cast(unsigned int, f);
  return (unsigned short)((u + 0x7fffu + ((u >> 16) & 1u)) >> 16);  // RNE
}

__device__ __forceinline__ u16x8 pack8(float4 a, float4 b) {
  u16x8 v;
  v[0] = f2bf(a.x); v[1] = f2bf(a.y); v[2] = f2bf(a.z); v[3] = f2bf(a.w);
  v[4] = f2bf(b.x); v[5] = f2bf(b.y); v[6] = f2bf(b.z); v[7] = f2bf(b.w);
  return v;
}

__device__ __forceinline__ unsigned short cvt1(float f) {
  __hip_bfloat16 h = __float2bfloat16(f);          // compiler-lowered RNE cvt
  return __builtin_bit_cast(unsigned short, h);
}

#define SCHEDB()  __builtin_amdgcn_sched_barrier(0)

// wconvert: w [512][1024] f32 -> wb in MFMA-fragment-major bf16 layout.
// unit uid = (s*32 + nf)*64 + lane   (16 B each; s = k-slice 0..31, nf = n-frag)
// holds w[n = nf*16 + (lane&15)][k = s*32 + (lane>>4)*8 + e], e = 0..7.
__global__ void wconvert_kernel(const float* __restrict__ w,
                                unsigned short* __restrict__ wb) {
  int uid = blockIdx.x * blockDim.x + threadIdx.x;   // 0..65535
  int s   = uid >> 11;
  int nf  = (uid >> 6) & 31;
  int l   = uid & 63;
  int n   = nf * 16 + (l & 15);
  int k0  = s * 32 + (l >> 4) * 8;
  const float* src = w + n * KD + k0;
  float4 a = *reinterpret_cast<const float4*>(src);
  float4 b = *reinterpret_cast<const float4*>(src + 4);
  *reinterpret_cast<u16x8*>(wb + (size_t)uid * 8) = pack8(a, b);
}

// ===== Fused GEMM(64x512, full N) + bias + LN + scale + softmax =============
// R4: 512 thr / 8 waves (1M x 8N), wave tile 64x64, acc[4][4] (64 VGPR).
// B: NO LDS — fragment-major wb, coalesced dwordx4 global->reg, reg-dbuf
//    one tile ahead (L2-resident 1 MB; compiler-tracked waits, no drains).
// A: LDS dbuf 2 x 4 KB (64 rows x 32 k bf16), XOR-swizzled chunks, one
//    float4 gload + cvt + ds_write_b64 per thread per tile.
// LDS total 8 KB -> 2 blocks/CU: independent blocks overlap each other's
// barrier stalls (the m114 mechanism R1-R3 lacked at 1 block/CU).
__global__ __launch_bounds__(512, 4)
void fused_kernel(const float* __restrict__ x,
                  const unsigned short* __restrict__ wb,
                  const float* __restrict__ bias,
                  const float* __restrict__ gamma,
                  const float* __restrict__ beta,
                  const float* __restrict__ scalep,
                  float* __restrict__ out) {
  __shared__ unsigned short As[2][64 * 32];    // 4 KB each

  const int tid  = threadIdx.x;
  const int lane = tid & 63;
  const int wid  = tid >> 6;        // 0..7 = N eighth: cols wid*64..+63
  const int l15  = lane & 15;
  const int lg   = lane >> 4;       // 0..3

  const long bm  = (long)blockIdx.x * 64;

  f32x4 acc[4][4] = {};

  // ---- A staging: thread t loads x[bm + (t>>3)][ (t&7)*4 .. +3 ] per tile.
  //      LDS row = 64 B = 4 chunks of 16 B; chunk c at c ^ ((row>>1)&3).
  const int arow = tid >> 3;
  const int akq  = tid & 7;
  const float* asrc = x + (bm + arow) * KD + akq * 4;
  const int awb = arow * 64 + (((akq >> 1) ^ ((arow >> 1) & 3)) * 16)
                + ((akq & 1) * 8);

  // ---- A fragment read offsets: lane holds A[mi*16+l15][k = lg*8..+7] ----
  const int swa = (lg ^ ((l15 >> 1) & 3)) * 16;
  int ard[4];
  #pragma unroll
  for (int mi = 0; mi < 4; ++mi) ard[mi] = (mi * 16 + l15) * 64 + swa;

  // ---- B fragment base: frag ni of tile t at ((t*32 + wid*4+ni)*64+lane)*8 us
  const unsigned short* bbase = wb + ((size_t)(wid * 4) * 64 + lane) * 8;

#define LOADA(t) (*reinterpret_cast<const float4*>(asrc + (t) * 32))

#define LOADB(t, r0, r1, r2, r3) do { \
    const unsigned short* bp_ = bbase + (t) * 16384; \
    r0 = *reinterpret_cast<const bf16x8*>(bp_ + 0 * 512); \
    r1 = *reinterpret_cast<const bf16x8*>(bp_ + 1 * 512); \
    r2 = *reinterpret_cast<const bf16x8*>(bp_ + 2 * 512); \
    r3 = *reinterpret_cast<const bf16x8*>(bp_ + 3 * 512); } while (0)

#define WRITE_A(bufi) do { \
    union { unsigned short s[4]; unsigned long long v; } c_; \
    c_.s[0] = cvt1(qa.x); c_.s[1] = cvt1(qa.y); \
    c_.s[2] = cvt1(qa.z); c_.s[3] = cvt1(qa.w); \
    *reinterpret_cast<unsigned long long*>((char*)As[bufi] + awb) = c_.v; } while (0)

#define COMPUTE(bufi, B0, B1, B2, B3) do { \
    const char* ab_ = (const char*)As[bufi]; \
    bf16x8 a0_ = *reinterpret_cast<const bf16x8*>(ab_ + ard[0]); \
    bf16x8 a1_ = *reinterpret_cast<const bf16x8*>(ab_ + ard[1]); \
    bf16x8 a2_ = *reinterpret_cast<const bf16x8*>(ab_ + ard[2]); \
    bf16x8 a3_ = *reinterpret_cast<const bf16x8*>(ab_ + ard[3]); \
    acc[0][0] = __builtin_amdgcn_mfma_f32_16x16x32_bf16(a0_, B0, acc[0][0], 0, 0, 0); \
    acc[0][1] = __builtin_amdgcn_mfma_f32_16x16x32_bf16(a0_, B1, acc[0][1], 0, 0, 0); \
    acc[0][2] = __builtin_amdgcn_mfma_f32_16x16x32_bf16(a0_, B2, acc[0][2], 0, 0, 0); \
    acc[0][3] = __builtin_amdgcn_mfma_f32_16x16x32_bf16(a0_, B3, acc[0][3], 0, 0, 0); \
    acc[1][0] = __builtin_amdgcn_mfma_f32_16x16x32_bf16(a1_, B0, acc[1][0], 0, 0, 0); \
    acc[1][1] = __builtin_amdgcn_mfma_f32_16x16x32_bf16(a1_, B1, acc[1][1], 0, 0, 0); \
    acc[1][2] = __builtin_amdgcn_mfma_f32_16x16x32_bf16(a1_, B2, acc[1][2], 0, 0, 0); \
    acc[1][3] = __builtin_amdgcn_mfma_f32_16x16x32_bf16(a1_, B3, acc[1][3], 0, 0, 0); \
    acc[2][0] = __builtin_amdgcn_mfma_f32_16x16x32_bf16(a2_, B0, acc[2][0], 0, 0, 0); \
    acc[2][1] = __builtin_amdgcn_mfma_f32_16x16x32_bf16(a2_, B1, acc[2][1], 0, 0, 0); \
    acc[2][2] = __builtin_amdgcn_mfma_f32_16x16x32_bf16(a2_, B2, acc[2][2], 0, 0, 0); \
    acc[2][3] = __builtin_amdgcn_mfma_f32_16x16x32_bf16(a2_, B3, acc[2][3], 0, 0, 0); \
    acc[3][0] = __builtin_amdgcn_mfma_f32_16x16x32_bf16(a3_, B0, acc[3][0], 0, 0, 0); \
    acc[3][1] = __builtin_amdgcn_mfma_f32_16x16x32_bf16(a3_, B1, acc[3][1], 0, 0, 0); \
    acc[3][2] = __builtin_amdgcn_mfma_f32_16x16x32_bf16(a3_, B2, acc[3][2], 0, 0, 0); \
    acc[3][3] = __builtin_amdgcn_mfma_f32_16x16x32_bf16(a3_, B3, acc[3][3], 0, 0, 0); \
    } while (0)

  float4 qa;
  bf16x8 bc0, bc1, bc2, bc3, bn0, bn1, bn2, bn3;

  // ---- prologue: A(0) -> LDS buf0, B(0) -> regs ----
  qa = LOADA(0);
  LOADB(0, bc0, bc1, bc2, bc3);
  WRITE_A(0);
  __syncthreads();

  for (int t = 0; t < NT; t += 2) {
    const int tp1 = (t + 1 < NT) ? t + 1 : NT - 1;   // clamp: redundant tail ok
    const int tp2 = (t + 2 < NT) ? t + 2 : NT - 1;
    qa = LOADA(tp1);
    LOADB(tp1, bn0, bn1, bn2, bn3);
    SCHEDB();                       // keep next-tile loads issued early
    COMPUTE(0, bc0, bc1, bc2, bc3); // tile t (even) from buf 0
    WRITE_A(1);                     // A(t+1) -> buf 1
    __syncthreads();
    qa = LOADA(tp2);
    LOADB(tp2, bc0, bc1, bc2, bc3);
    SCHEDB();
    COMPUTE(1, bn0, bn1, bn2, bn3); // tile t+1 from buf 1
    WRITE_A(0);                     // A(t+2) -> buf 0
    __syncthreads();
  }

  // ================= fused epilogue: bias + LN + scale + softmax ============
  // scratch overlaps As (8 KB): redS [64][9], redQ [64][9], rowA/rowB [64]
  float* redS = (float*)As[0];
  float* redQ = redS + 576;
  float* rowA = redQ + 576;
  float* rowB = rowA + 64;

  const int col0 = wid * 64 + l15;
  const float sc = scalep[0];
  float bs4[4], gs4[4], bb4[4];
  #pragma unroll
  for (int ni = 0; ni < 4; ++ni) {
    bs4[ni] = bias[col0 + ni * 16];
    gs4[ni] = gamma[col0 + ni * 16] * sc;
    bb4[ni] = beta[col0 + ni * 16] * sc;
  }

  // ---- bias add + per-row sum / sumsq ----
  #pragma unroll
  for (int mi = 0; mi < 4; ++mi) {
    #pragma unroll
    for (int j = 0; j < 4; ++j) {
      float s = 0.f, q = 0.f;
      #pragma unroll
      for (int ni = 0; ni < 4; ++ni) {
        float v = acc[mi][ni][j] + bs4[ni];
        acc[mi][ni][j] = v;
        s += v;
        q = fmaf(v, v, q);
      }
      #pragma unroll
      for (int m = 1; m < 16; m <<= 1) {
        s += __shfl_xor(s, m, 64);
        q += __shfl_xor(q, m, 64);
      }
      if (l15 == 0) {
        int r = mi * 16 + lg * 4 + j;
        redS[r * 9 + wid] = s;
        redQ[r * 9 + wid] = q;
      }
    }
  }
  __syncthreads();
  if (tid < 64) {
    float s = 0.f, q = 0.f;
    #pragma unroll
    for (int k = 0; k < 8; ++k) { s += redS[tid * 9 + k]; q += redQ[tid * 9 + k]; }
    float mu = s * (1.f / ND);
    rowA[tid] = mu;
    rowB[tid] = rsqrtf(q * (1.f / ND) - mu * mu + EPSV);
  }
  __syncthreads();

  // ---- normalize + scale; per-row max ----
  #pragma unroll
  for (int mi = 0; mi < 4; ++mi) {
    #pragma unroll
    for (int j = 0; j < 4; ++j) {
      int r = mi * 16 + lg * 4 + j;
      float mu = rowA[r], rs = rowB[r];
      float pm = -3.402823466e38f;
      #pragma unroll
      for (int ni = 0; ni < 4; ++ni) {
        float v = (acc[mi][ni][j] - mu) * rs;
        v = fmaf(v, gs4[ni], bb4[ni]);
        acc[mi][ni][j] = v;
        pm = fmaxf(pm, v);
      }
      #pragma unroll
      for (int m = 1; m < 16; m <<= 1) pm = fmaxf(pm, __shfl_xor(pm, m, 64));
      if (l15 == 0) redS[r * 9 + wid] = pm;
    }
  }
  __syncthreads();
  if (tid < 64) {
    float m0 = fmaxf(fmaxf(redS[tid * 9 + 0], redS[tid * 9 + 1]),
                     fmaxf(redS[tid * 9 + 2], redS[tid * 9 + 3]));
    float m1 = fmaxf(fmaxf(redS[tid * 9 + 4], redS[tid * 9 + 5]),
                     fmaxf(redS[tid * 9 + 6], redS[tid * 9 + 7]));
    rowA[tid] = fmaxf(m0, m1);
  }
  __syncthreads();

  // ---- exp + per-row sum ----
  #pragma unroll
  for (int mi = 0; mi < 4; ++mi) {
    #pragma unroll
    for (int j = 0; j < 4; ++j) {
      int r = mi * 16 + lg * 4 + j;
      float rmx = rowA[r];
      float ps = 0.f;
      #pragma unroll
      for (int ni = 0; ni < 4; ++ni) {
        float e = __expf(acc[mi][ni][j] - rmx);
        acc[mi][ni][j] = e;
        ps += e;
      }
      #pragma unroll
      for (int m = 1; m < 16; m <<= 1) ps += __shfl_xor(ps, m, 64);
      if (l15 == 0) redQ[r * 9 + wid] = ps;
    }
  }
  __syncthreads();
  if (tid < 64) {
    float s = 0.f;
    #pragma unroll
    for (int k = 0; k < 8; ++k) s += redQ[tid * 9 + k];
    rowB[tid] = 1.f / s;
  }
  __syncthreads();

  // ---- store out f32 (non-temporal) ----
  #pragma unroll
  for (int mi = 0; mi < 4; ++mi) {
    #pragma unroll
    for (int j = 0; j < 4; ++j) {
      int r = mi * 16 + lg * 4 + j;
      float rd = rowB[r];
      float* op = out + (bm + r) * ND + col0;
      #pragma unroll
      for (int ni = 0; ni < 4; ++ni)
        __builtin_nontemporal_store(acc[mi][ni][j] * rd, op + ni * 16);
    }
  }
#undef LOADA
#undef LOADB
#undef WRITE_A
#undef COMPUTE
}

// trivial last-resort fallback (ws too small; not expected in this harness)
__global__ void fused_fallback(const float* __restrict__ x,
                               const float* __restrict__ wf,
                               const float* __restrict__ bias,
                               const float* __restrict__ gamma,
                               const float* __restrict__ beta,
                               const float* __restrict__ scalep,
                               float* __restrict__ out) {
  long row = blockIdx.x;
  int t = threadIdx.x;
  float s = 0.f;
  const float* xr = x + row * KD;
  const float* wr_ = wf + (size_t)t * KD;
  for (int k = 0; k < KD; ++k) s += xr[k] * wr_[k];
  s += bias[t];
  __shared__ float buf[ND];
  buf[t] = s;
  __syncthreads();
  __shared__ float red[2];
  if (t == 0) {
    float sum = 0.f, sq = 0.f;
    for (int i = 0; i < ND; ++i) { sum += buf[i]; sq += buf[i] * buf[i]; }
    float mu = sum / ND;
    red[0] = mu;
    red[1] = rsqrtf(sq / ND - mu * mu + EPSV);
  }
  __syncthreads();
  float zv = (s - red[0]) * red[1] * gamma[t] * scalep[0] + beta[t] * scalep[0];
  buf[t] = zv;
  __syncthreads();
  __shared__ float red2[2];
  if (t == 0) {
    float mxv = -3.4e38f;
    for (int i = 0; i < ND; ++i) mxv = fmaxf(mxv, buf[i]);
    float den = 0.f;
    for (int i = 0; i < ND; ++i) den += __expf(buf[i] - mxv);
    red2[0] = mxv; red2[1] = 1.f / den;
  }
  __syncthreads();
  out[row * ND + t] = __expf(zv - red2[0]) * red2[1];
}

extern "C" void kernel_launch(void* const* d_in, const int* in_sizes, int n_in,
                              void* d_out, int out_size, void* d_ws, size_t ws_size,
                              hipStream_t stream) {
  const float* x     = (const float*)d_in[0];
  const float* w     = (const float*)d_in[1];
  const float* bias  = (const float*)d_in[2];
  const float* gamma = (const float*)d_in[3];
  const float* beta  = (const float*)d_in[4];
  const float* scale = (const float*)d_in[5];
  float* out = (float*)d_out;

  const int Mrows = in_sizes[0] / KD;                                  // 65536
  const size_t wb_bytes = (size_t)ND * KD * sizeof(unsigned short);    // 1 MB

  if (ws_size >= wb_bytes) {
    unsigned short* wbuf = (unsigned short*)d_ws;
    wconvert_kernel<<<(ND * KD / 8) / 256, 256, 0, stream>>>(w, wbuf);
    fused_kernel<<<Mrows / 64, 512, 0, stream>>>(x, wbuf, bias, gamma, beta,
                                                 scale, out);
  } else {
    fused_fallback<<<Mrows, ND, 0, stream>>>(x, w, bias, gamma, beta, scale, out);
  }
}